// Round 14
// baseline (1166.783 us; speedup 1.0000x reference)
//
#include <hip/hip_runtime.h>

#define TT 2048
#define HH 64
#define II 6
#define OO 6
#define NTHR 512   // 8 waves: 4 A-waves (layer0 + FC1 + FC2@w0), 4 B-waves (layer1)

typedef float    f32x4 __attribute__((ext_vector_type(4)));
typedef float    f32x2 __attribute__((ext_vector_type(2)));
typedef _Float16 f16x8 __attribute__((ext_vector_type(8)));

__device__ __forceinline__ float fast_sig(float v) {
    return __builtin_amdgcn_rcpf(1.0f + __expf(-v));
}
__device__ __forceinline__ float fast_tanh(float v) {
    return 1.0f - 2.0f * __builtin_amdgcn_rcpf(__expf(2.0f * v) + 1.0f);
}

#define MFMA(a, b, c) __builtin_amdgcn_mfma_f32_16x16x32_f16((a), (b), (c), 0, 0, 0)

// LDS-only barrier: global loads/stores stay in flight across it.
#define LGKM_BARRIER() asm volatile("s_waitcnt lgkmcnt(0)\ns_barrier" ::: "memory")

// steady-state sub-step: ALL slots are compile-time literals, NO bounds checks
#define STEP_STEADY(S, RP, WS, RPB, P1, P0)                                       \
  {                                                                               \
    if (isA) {                                                                    \
      const f16x8 a0  = *reinterpret_cast<const f16x8*>(&H0[RP][8 * q]);          \
      const f16x8 a1  = *reinterpret_cast<const f16x8*>(&H0[RP][32 + 8 * q]);     \
      const f16x8 b0f = *reinterpret_cast<const f16x8*>(&H1[P1][8 * q]);          \
      const f16x8 b1f = *reinterpret_cast<const f16x8*>(&H1[P1][32 + 8 * q]);     \
      float gv[4];                                                                \
      _Pragma("unroll")                                                           \
      for (int g = 0; g < 4; ++g) {                                               \
        f32x4 acc0 = MFMA(a0, fragG[2 * g + 0], zero4);                           \
        f32x4 acc1 = MFMA(a1, fragG[2 * g + 1], zero4);                           \
        float xd = b0j[g];                                                        \
        _Pragma("unroll")                                                         \
        for (int k2 = 0; k2 < 6; ++k2) xd = fmaf(wx[g][k2], xv[S][k2], xd);       \
        gv[g] = (acc0[0] + acc1[0]) + xd;                                         \
      }                                                                           \
      f32x4 f0 = MFMA(b0f, fragX[0], biasX);                                      \
      f32x4 f1 = MFMA(b1f, fragX[1], zero4);                                      \
      if (w == 0) {                                                               \
        const f16x8 r0 = *reinterpret_cast<const f16x8*>(&Rb[P0][8 * q]);         \
        const f16x8 r1 = *reinterpret_cast<const f16x8*>(&Rb[P0][32 + 8 * q]);    \
        f32x4 o0 = MFMA(r0, fragY[0], biasY);                                     \
        f32x4 o1 = MFMA(r1, fragY[1], zero4);                                     \
        if (lane < OO) op[OO * (S) + lane] = o0[0] + o1[0];                       \
      }                                                                           \
      float i_ = fast_sig(gv[0]), f_ = fast_sig(gv[1]);                           \
      float g_ = fast_tanh(gv[2]), o_ = fast_sig(gv[3]);                          \
      cst = f_ * cst + i_ * g_;                                                   \
      float h = o_ * fast_tanh(cst);                                              \
      if (lane < 16) {                                                            \
        H0[WS][16 * w + lane] = (_Float16)h;                                      \
        Rb[P1][16 * w + lane] = (_Float16)fmaxf(f0[0] + f1[0], 0.f);              \
      }                                                                           \
    } else {                                                                      \
      const f16x8 h00 = *reinterpret_cast<const f16x8*>(&H0[RPB][8 * q]);         \
      const f16x8 h01 = *reinterpret_cast<const f16x8*>(&H0[RPB][32 + 8 * q]);    \
      const f16x8 a0  = *reinterpret_cast<const f16x8*>(&H1[P1][8 * q]);          \
      const f16x8 a1  = *reinterpret_cast<const f16x8*>(&H1[P1][32 + 8 * q]);     \
      float gv[4];                                                                \
      _Pragma("unroll")                                                           \
      for (int g = 0; g < 4; ++g) {                                               \
        f32x4 acc0 = MFMA(h00, fragG[4 * g + 0], biasv[g]);                       \
        f32x4 acc1 = MFMA(h01, fragG[4 * g + 1], zero4);                          \
        f32x4 acc2 = MFMA(a0,  fragG[4 * g + 2], zero4);                          \
        f32x4 acc3 = MFMA(a1,  fragG[4 * g + 3], zero4);                          \
        gv[g] = (acc0[0] + acc1[0]) + (acc2[0] + acc3[0]);                        \
      }                                                                           \
      float i_ = fast_sig(gv[0]), f_ = fast_sig(gv[1]);                           \
      float g_ = fast_tanh(gv[2]), o_ = fast_sig(gv[3]);                          \
      cst = f_ * cst + i_ * g_;                                                   \
      float h = o_ * fast_tanh(cst);                                              \
      if (lane < 16) H1[P0][16 * w + lane] = (_Float16)h;                         \
    }                                                                             \
    LGKM_BARRIER();                                                               \
  }

__global__
__attribute__((amdgpu_flat_work_group_size(NTHR, NTHR)))
__attribute__((amdgpu_waves_per_eu(2, 2)))
void lstm_mfma_kernel(const float* __restrict__ x,
                      const float* __restrict__ Wih0, const float* __restrict__ Whh0,
                      const float* __restrict__ b0,
                      const float* __restrict__ Wih1, const float* __restrict__ Whh1,
                      const float* __restrict__ b1,
                      const float* __restrict__ W1, const float* __restrict__ bf1,
                      const float* __restrict__ W2, const float* __restrict__ bf2,
                      float* __restrict__ out)
{
    const int row  = blockIdx.x;      // one batch row per block
    const int tid  = threadIdx.x;
    const int wid  = tid >> 6;        // wave id 0..7
    const int lane = tid & 63;
    const int n    = lane & 15;       // MFMA col-lane (B-col / D-col)
    const int q    = lane >> 4;       // k-group: lane holds k = 8q..8q+7 (+32 for hi)
    const bool isA = wid < 4;
    const int  w   = isA ? wid : wid - 4;   // role-local wave index 0..3

    // h0: 4 slots (A writes t&3, A reads (t+3)&3 = t-1, B reads (t+2)&3 = t-2)
    __shared__ __attribute__((aligned(16))) _Float16 H0[4][HH];
    __shared__ __attribute__((aligned(16))) _Float16 H1[2][HH];
    __shared__ __attribute__((aligned(16))) _Float16 Rb[2][HH];

    if (tid < HH) {
        H0[0][tid] = (_Float16)0.f; H0[1][tid] = (_Float16)0.f;
        H0[2][tid] = (_Float16)0.f; H0[3][tid] = (_Float16)0.f;
        H1[0][tid] = (_Float16)0.f; H1[1][tid] = (_Float16)0.f;
        Rb[0][tid] = (_Float16)0.f; Rb[1][tid] = (_Float16)0.f;
    }

    // elem i <-> k = kbase + 8q + i (same map for A-frag reads, so it cancels)
    auto mk = [&](const float* W, int r, int ld, int kbase, int kmax, bool rok) {
        f16x8 f;
        #pragma unroll
        for (int i = 0; i < 8; ++i) {
            int kk = kbase + 8 * q + i;
            f[i] = (rok && kk < kmax) ? (_Float16)W[r * ld + kk] : (_Float16)0.f;
        }
        return f;
    };
    auto splat = [](float v) { f32x4 r = {v, v, v, v}; return r; };

    f16x8 fragG[16], fragX[2], fragY[2];
    f32x4 biasv[4], biasX, biasY;
    float b0j[4];
    float wx[4][6];
    const f32x4 zero4 = {0.f, 0.f, 0.f, 0.f};

    if (isA) {
        #pragma unroll
        for (int g = 0; g < 4; ++g) {           // layer0 gates: 2 independent chunks
            const int r0 = g * HH + 16 * w + n; // gate row (i,f,g,o stacked)
            fragG[2 * g + 0] = mk(Whh0, r0, HH, 0,  HH, true);
            fragG[2 * g + 1] = mk(Whh0, r0, HH, 32, HH, true);
            b0j[g] = b0[r0];
            #pragma unroll
            for (int k2 = 0; k2 < 6; ++k2) wx[g][k2] = Wih0[r0 * II + k2];
        }
        #pragma unroll
        for (int i = 8; i < 16; ++i) fragG[i] = fragG[0];   // unused
        const int rf = 16 * w + n;              // FC1 row
        fragX[0] = mk(W1, rf, HH, 0,  HH, true);
        fragX[1] = mk(W1, rf, HH, 32, HH, true);
        biasX = splat(bf1[rf]);
        fragY[0] = mk(W2, n, HH, 0,  HH, n < OO);   // FC2 (only w0 uses)
        fragY[1] = mk(W2, n, HH, 32, HH, n < OO);
        biasY = splat((n < OO) ? bf2[n] : 0.f);
        #pragma unroll
        for (int g = 0; g < 4; ++g) biasv[g] = zero4;   // unused on A
    } else {
        #pragma unroll
        for (int g = 0; g < 4; ++g) {           // layer1: fused, 4 independent chunks
            const int r0 = g * HH + 16 * w + n;
            fragG[4 * g + 0] = mk(Wih1, r0, HH, 0,  HH, true);   // @ h0[t-2]
            fragG[4 * g + 1] = mk(Wih1, r0, HH, 32, HH, true);
            fragG[4 * g + 2] = mk(Whh1, r0, HH, 0,  HH, true);   // @ h1[t-3]
            fragG[4 * g + 3] = mk(Whh1, r0, HH, 32, HH, true);
            biasv[g] = splat(b1[r0]);
            b0j[g] = 0.f;
            #pragma unroll
            for (int k2 = 0; k2 < 6; ++k2) wx[g][k2] = 0.f;
        }
        fragX[0] = fragG[0]; fragX[1] = fragG[1];
        fragY[0] = fragG[0]; fragY[1] = fragG[1];
        biasX = zero4; biasY = zero4;
    }

    // x pointer opaqued to VGPR: forces vector (vmcnt) loads, keeps them lazy
    const float* xrow = x + (size_t)row * TT * II;
    {
        unsigned long long p = (unsigned long long)xrow;
        asm volatile("" : "+v"(p));
        xrow = (const float*)p;
    }
    float* outrow = out + (size_t)row * TT * OO;
    float* op = nullptr;

    float xv[5][6];   // xv[0] = carry (x[tb]); xv[1..4] = x[tb+1..tb+4]
    #pragma unroll
    for (int s = 0; s < 5; ++s)
        #pragma unroll
        for (int k2 = 0; k2 < 6; ++k2) xv[s][k2] = 0.f;

    float cst = 0.f;   // cell state: A lanes 0-15 hold c0; B lanes 0-15 hold c1

    __syncthreads();

    // checked step for prologue / tail (runtime t, full bounds)
    auto step_checked = [&](int t) {
        const int RP = (t + 3) & 3, WS = t & 3, RPB = (t + 2) & 3;
        const int P1 = (t + 1) & 1, P0 = t & 1;
        if (isA) {
            const f16x8 a0  = *reinterpret_cast<const f16x8*>(&H0[RP][8 * q]);
            const f16x8 a1  = *reinterpret_cast<const f16x8*>(&H0[RP][32 + 8 * q]);
            const f16x8 b0f = *reinterpret_cast<const f16x8*>(&H1[P1][8 * q]);
            const f16x8 b1f = *reinterpret_cast<const f16x8*>(&H1[P1][32 + 8 * q]);
            float xs[6] = {0.f, 0.f, 0.f, 0.f, 0.f, 0.f};
            if (t < TT) {
                const float* xp = xrow + (size_t)t * II;
                #pragma unroll
                for (int k2 = 0; k2 < 6; ++k2) xs[k2] = xp[k2];
            }
            float gv[4];
            #pragma unroll
            for (int g = 0; g < 4; ++g) {
                f32x4 acc0 = MFMA(a0, fragG[2 * g + 0], zero4);
                f32x4 acc1 = MFMA(a1, fragG[2 * g + 1], zero4);
                float xd = b0j[g];
                #pragma unroll
                for (int k2 = 0; k2 < 6; ++k2) xd = fmaf(wx[g][k2], xs[k2], xd);
                gv[g] = (acc0[0] + acc1[0]) + xd;
            }
            f32x4 f0 = MFMA(b0f, fragX[0], biasX);
            f32x4 f1 = MFMA(b1f, fragX[1], zero4);
            const int s4 = t - 4;
            if (w == 0 && s4 >= 0 && s4 < TT) {
                const f16x8 r0 = *reinterpret_cast<const f16x8*>(&Rb[P0][8 * q]);
                const f16x8 r1 = *reinterpret_cast<const f16x8*>(&Rb[P0][32 + 8 * q]);
                f32x4 o0 = MFMA(r0, fragY[0], biasY);
                f32x4 o1 = MFMA(r1, fragY[1], zero4);
                if (lane < OO) outrow[(size_t)s4 * OO + lane] = o0[0] + o1[0];
            }
            if (t < TT) {
                float i_ = fast_sig(gv[0]), f_ = fast_sig(gv[1]);
                float g_ = fast_tanh(gv[2]), o_ = fast_sig(gv[3]);
                cst = f_ * cst + i_ * g_;
                float h = o_ * fast_tanh(cst);
                if (lane < 16) H0[WS][16 * w + lane] = (_Float16)h;
            }
            const int s3 = t - 3;
            if (s3 >= 0 && s3 < TT && lane < 16)
                Rb[P1][16 * w + lane] = (_Float16)fmaxf(f0[0] + f1[0], 0.f);
        } else {
            const int s2 = t - 2;
            const f16x8 h00 = *reinterpret_cast<const f16x8*>(&H0[RPB][8 * q]);
            const f16x8 h01 = *reinterpret_cast<const f16x8*>(&H0[RPB][32 + 8 * q]);
            const f16x8 a0  = *reinterpret_cast<const f16x8*>(&H1[P1][8 * q]);
            const f16x8 a1  = *reinterpret_cast<const f16x8*>(&H1[P1][32 + 8 * q]);
            float gv[4];
            #pragma unroll
            for (int g = 0; g < 4; ++g) {
                f32x4 acc0 = MFMA(h00, fragG[4 * g + 0], biasv[g]);
                f32x4 acc1 = MFMA(h01, fragG[4 * g + 1], zero4);
                f32x4 acc2 = MFMA(a0,  fragG[4 * g + 2], zero4);
                f32x4 acc3 = MFMA(a1,  fragG[4 * g + 3], zero4);
                gv[g] = (acc0[0] + acc1[0]) + (acc2[0] + acc3[0]);
            }
            if (s2 >= 0 && s2 < TT) {
                float i_ = fast_sig(gv[0]), f_ = fast_sig(gv[1]);
                float g_ = fast_tanh(gv[2]), o_ = fast_sig(gv[3]);
                cst = f_ * cst + i_ * g_;
                float h = o_ * fast_tanh(cst);
                if (lane < 16) H1[P0][16 * w + lane] = (_Float16)h;
            }
        }
        LGKM_BARRIER();
    };

    // ---- prologue t = 0..3
    for (int t = 0; t < 4; ++t) step_checked(t);

    // carry-in x[4]
    if (isA) {
        const float* xp = xrow + (size_t)4 * II;
        #pragma unroll
        for (int k2 = 0; k2 < 6; ++k2) xv[0][k2] = xp[k2];
    }

    // ---- steady t = 4 .. 2043 (tb multiple of 4; all bounds const-true)
    for (int tb = 4; tb <= TT - 8; tb += 4) {
        if (isA) {
            const float* xp = xrow + (size_t)tb * II;
            f32x4 La = *reinterpret_cast<const f32x4*>(xp + 6);
            f32x2 Lb = *reinterpret_cast<const f32x2*>(xp + 10);
            f32x4 Ma = *reinterpret_cast<const f32x4*>(xp + 12);
            f32x2 Mb = *reinterpret_cast<const f32x2*>(xp + 16);
            f32x4 Na = *reinterpret_cast<const f32x4*>(xp + 18);
            f32x2 Nb = *reinterpret_cast<const f32x2*>(xp + 22);
            f32x4 Pa = *reinterpret_cast<const f32x4*>(xp + 24);
            f32x2 Pb = *reinterpret_cast<const f32x2*>(xp + 28);
            xv[1][0]=La[0]; xv[1][1]=La[1]; xv[1][2]=La[2]; xv[1][3]=La[3];
            xv[1][4]=Lb[0]; xv[1][5]=Lb[1];
            xv[2][0]=Ma[0]; xv[2][1]=Ma[1]; xv[2][2]=Ma[2]; xv[2][3]=Ma[3];
            xv[2][4]=Mb[0]; xv[2][5]=Mb[1];
            xv[3][0]=Na[0]; xv[3][1]=Na[1]; xv[3][2]=Na[2]; xv[3][3]=Na[3];
            xv[3][4]=Nb[0]; xv[3][5]=Nb[1];
            xv[4][0]=Pa[0]; xv[4][1]=Pa[1]; xv[4][2]=Pa[2]; xv[4][3]=Pa[3];
            xv[4][4]=Pb[0]; xv[4][5]=Pb[1];
            op = outrow + (size_t)(tb - 4) * OO;
        }
        STEP_STEADY(0, 3, 0, 2, 1, 0)
        STEP_STEADY(1, 0, 1, 3, 0, 1)
        STEP_STEADY(2, 1, 2, 0, 1, 0)
        STEP_STEADY(3, 2, 3, 1, 0, 1)
        if (isA) {
            #pragma unroll
            for (int k2 = 0; k2 < 6; ++k2) xv[0][k2] = xv[4][k2];
        }
    }

    // ---- tail t = 2044 .. 2051
    for (int t = TT - 4; t <= TT + 3; ++t) step_checked(t);
}

extern "C" void kernel_launch(void* const* d_in, const int* in_sizes, int n_in,
                              void* d_out, int out_size, void* d_ws, size_t ws_size,
                              hipStream_t stream) {
    const float* xp   = (const float*)d_in[0];
    const float* Wih0 = (const float*)d_in[1];
    const float* Whh0 = (const float*)d_in[2];
    const float* b0   = (const float*)d_in[3];
    const float* Wih1 = (const float*)d_in[4];
    const float* Whh1 = (const float*)d_in[5];
    const float* b1   = (const float*)d_in[6];
    const float* W1   = (const float*)d_in[7];
    const float* bf1  = (const float*)d_in[8];
    const float* W2   = (const float*)d_in[9];
    const float* bf2  = (const float*)d_in[10];
    float* outp = (float*)d_out;

    lstm_mfma_kernel<<<dim3(256), dim3(NTHR), 0, stream>>>(
        xp, Wih0, Whh0, b0, Wih1, Whh1, b1, W1, bf1, W2, bf2, outp);
}